// Round 1
// baseline (60.366 us; speedup 1.0000x reference)
//
#include <hip/hip_runtime.h>

// ExplicitSpacialEncoding: out[b, c*9+d] = sum_hw fcn[b,c,hw] * kern[c*9+d, hw],
// then L2-normalize over the 1152-wide row. All fp32.
// B=4096, C=128, D=9, HW=64.

constexpr int B_TOT   = 4096;
constexpr int C_CH    = 128;
constexpr int D_EMB   = 9;
constexpr int HW4     = 16;              // 64 floats = 16 float4
constexpr int BT      = 8;               // batch rows per block
constexpr int CC      = 32;              // channels per LDS chunk
constexpr int NCHUNK  = C_CH / CC;       // 4
constexpr int THREADS = BT * CC;         // 256
constexpr int CSTR4   = D_EMB * HW4 + 2; // 146 float4 per channel (pad 2 -> bank shift 8)

__global__ __launch_bounds__(THREADS, 2)
void esenc_kernel(const float* __restrict__ fcn,
                  const float* __restrict__ kern,
                  float* __restrict__ out) {
    extern __shared__ float4 smem4[];
    float4* kern_lds = smem4;                        // CC * CSTR4 float4
    float*  red      = (float*)(smem4 + CC * CSTR4); // THREADS floats
    float*  invn     = red + THREADS;                // BT floats

    const int tid     = threadIdx.x;
    const int c_local = tid >> 3;        // 0..31
    const int b_local = tid & (BT - 1);  // 0..7
    const size_t b    = (size_t)blockIdx.x * BT + b_local;

    const float4* kern4 = (const float4*)kern;       // [C*D][16] float4

    float raw[NCHUNK * D_EMB];
    float sumsq = 0.0f;

#pragma unroll
    for (int k = 0; k < NCHUNK; ++k) {
        __syncthreads();  // previous chunk's LDS reads done before overwrite
        // stage CC channels of kern into LDS (coalesced float4)
        for (int i = tid; i < CC * D_EMB * HW4; i += THREADS) {
            int c2 = i / (D_EMB * HW4);
            int r  = i - c2 * (D_EMB * HW4);
            kern_lds[c2 * CSTR4 + r] =
                kern4[(size_t)(k * CC + c2) * (D_EMB * HW4) + r];
        }
        __syncthreads();

        const int c = k * CC + c_local;
        const float4* fp = (const float4*)(fcn + ((size_t)b * C_CH + c) * 64);
        const float4* kl = &kern_lds[c_local * CSTR4];

        float acc[D_EMB];
#pragma unroll
        for (int d = 0; d < D_EMB; ++d) acc[d] = 0.0f;

#pragma unroll
        for (int h = 0; h < 2; ++h) {   // two hw-halves to bound fcn register use
            float4 f[8];
#pragma unroll
            for (int q = 0; q < 8; ++q) f[q] = fp[h * 8 + q];
#pragma unroll
            for (int d = 0; d < D_EMB; ++d) {
                float a = acc[d];
#pragma unroll
                for (int q = 0; q < 8; ++q) {
                    float4 kv = kl[d * HW4 + h * 8 + q];  // wave: 8 distinct addrs, 2-way banks
                    a = fmaf(f[q].x, kv.x, a);
                    a = fmaf(f[q].y, kv.y, a);
                    a = fmaf(f[q].z, kv.z, a);
                    a = fmaf(f[q].w, kv.w, a);
                }
                acc[d] = a;
            }
        }
#pragma unroll
        for (int d = 0; d < D_EMB; ++d) {
            raw[k * D_EMB + d] = acc[d];
            sumsq = fmaf(acc[d], acc[d], sumsq);
        }
    }

    // row-wise sum of squares: 32 partials per row (one per channel-thread)
    red[tid] = sumsq;
    __syncthreads();
    if (tid < BT) {
        float s = 0.0f;
#pragma unroll
        for (int j = 0; j < CC; ++j) s += red[j * BT + tid];
        invn[tid] = 1.0f / sqrtf(s + 1e-10f);
    }
    __syncthreads();
    const float inv = invn[b_local];

#pragma unroll
    for (int k = 0; k < NCHUNK; ++k) {
        const int c = k * CC + c_local;
        float* op = out + b * (size_t)(C_CH * D_EMB) + c * D_EMB;
#pragma unroll
        for (int d = 0; d < D_EMB; ++d) op[d] = raw[k * D_EMB + d] * inv;
    }
}

extern "C" void kernel_launch(void* const* d_in, const int* in_sizes, int n_in,
                              void* d_out, int out_size, void* d_ws, size_t ws_size,
                              hipStream_t stream) {
    const float* fcn  = (const float*)d_in[0];   // [4096,128,8,8] f32
    const float* kern = (const float*)d_in[1];   // [1,1152,8,8]  f32
    float* out = (float*)d_out;                  // [4096,1152]   f32

    const size_t shmem = (size_t)CC * CSTR4 * sizeof(float4)
                       + THREADS * sizeof(float) + BT * sizeof(float);
    dim3 grid(B_TOT / BT), block(THREADS);
    hipLaunchKernelGGL(esenc_kernel, grid, block, shmem, stream, fcn, kern, out);
}

// Round 2
// 54.659 us; speedup vs baseline: 1.1044x; 1.1044x over previous
//
#include <hip/hip_runtime.h>

// out[b, c*9+d] = sum_hw fcn[b,c,hw] * kern[c*9+d, hw]; rows L2-normalized.
// B=4096, C=128, D=9, HW=64, all fp32.
//
// K1: block = 32 rows x 32 channels; thread = 4 rows x 1 channel (kern LDS
//     read reused 16x). Writes raw out + per-(row, ctile) sumsq partials to ws.
// K2: out *= rsqrt(sum of 4 partials + eps), in place.

constexpr int B_TOT = 4096;
constexpr int C_CH  = 128;
constexpr int D_EMB = 9;
constexpr int HW    = 64;
constexpr int HW4   = 16;                 // float4 per channel
constexpr int CC    = 32;                 // channels per block (c-tile)
constexpr int NCT   = C_CH / CC;          // 4 c-tiles
constexpr int BT    = 32;                 // rows per block
constexpr int NB    = 4;                  // rows per thread
constexpr int THREADS = 256;              // CC * (BT/NB)
constexpr int KSTR4 = D_EMB * HW4 + 1;    // 145 (odd float4 stride -> 2-way banks = free)

__global__ __launch_bounds__(THREADS)
void esenc_main(const float* __restrict__ fcn,
                const float* __restrict__ kern,
                float* __restrict__ out,
                float* __restrict__ partial) {
    __shared__ float4 klds[CC * KSTR4];               // 74240 B
    float* tile = (float*)klds;                        // reuse after compute: [BT][CC*D_EMB]
    float* red  = tile + BT * CC * D_EMB;              // [BT][CC]

    const int tid = threadIdx.x;
    const int cl  = tid & (CC - 1);                    // channel within tile
    const int bg  = tid >> 5;                          // row group 0..7
    const int bt  = blockIdx.x >> 2;
    const int ct  = blockIdx.x & 3;
    const int b0  = bt * BT;
    const int c   = ct * CC + cl;

    // stage kern tile once (no chunk loop, single barrier)
    const float4* kern4 = (const float4*)kern;
    for (int i = tid; i < CC * D_EMB * HW4; i += THREADS) {
        int c2 = i / (D_EMB * HW4);
        int r  = i - c2 * (D_EMB * HW4);
        klds[c2 * KSTR4 + r] = kern4[(size_t)(ct * CC + c2) * (D_EMB * HW4) + r];
    }
    __syncthreads();

    const float4* kl = &klds[cl * KSTR4];
    const int rbase  = b0 + bg * NB;

    const float4* fp[NB];
#pragma unroll
    for (int r = 0; r < NB; ++r)
        fp[r] = (const float4*)(fcn + ((size_t)(rbase + r) * C_CH + c) * HW);

    float acc[NB][D_EMB];
#pragma unroll
    for (int r = 0; r < NB; ++r)
#pragma unroll
        for (int d = 0; d < D_EMB; ++d) acc[r][d] = 0.0f;

#pragma unroll
    for (int h = 0; h < 4; ++h) {                      // 4 batches of 4 float4 per row
        float4 f[NB][4];
#pragma unroll
        for (int r = 0; r < NB; ++r)
#pragma unroll
            for (int i = 0; i < 4; ++i) f[r][i] = fp[r][h * 4 + i];
#pragma unroll
        for (int d = 0; d < D_EMB; ++d) {
#pragma unroll
            for (int i = 0; i < 4; ++i) {
                const float4 kv = kl[d * HW4 + h * 4 + i];   // one LDS read -> 16 FMA
#pragma unroll
                for (int r = 0; r < NB; ++r) {
                    float a = acc[r][d];
                    a = fmaf(f[r][i].x, kv.x, a);
                    a = fmaf(f[r][i].y, kv.y, a);
                    a = fmaf(f[r][i].z, kv.z, a);
                    a = fmaf(f[r][i].w, kv.w, a);
                    acc[r][d] = a;
                }
            }
        }
    }

    float part[NB];
#pragma unroll
    for (int r = 0; r < NB; ++r) {
        float s = 0.0f;
#pragma unroll
        for (int d = 0; d < D_EMB; ++d) s = fmaf(acc[r][d], acc[r][d], s);
        part[r] = s;
    }

    __syncthreads();   // done reading kern; reuse LDS

    // stage results into LDS for coalesced stores
#pragma unroll
    for (int r = 0; r < NB; ++r) {
        const int row = bg * NB + r;
#pragma unroll
        for (int d = 0; d < D_EMB; ++d)
            tile[row * (CC * D_EMB) + cl * D_EMB + d] = acc[r][d];  // 9c%32 distinct: ~2-way
        red[row * CC + cl] = part[r];
    }
    __syncthreads();

    // coalesced float4 stores: BT*288 floats = 2304 float4, 9 per thread
    const float4* t4 = (const float4*)tile;
    float4* out4 = (float4*)out;
#pragma unroll
    for (int j = 0; j < (BT * CC * D_EMB / 4) / THREADS; ++j) {
        const int idx = tid + j * THREADS;
        const int r   = idx / (CC * D_EMB / 4);        // /72
        const int off = idx - r * (CC * D_EMB / 4);
        out4[(size_t)(b0 + r) * (C_CH * D_EMB / 4) + ct * (CC * D_EMB / 4) + off] = t4[idx];
    }

    if (tid < BT) {
        float s = 0.0f;
#pragma unroll
        for (int j = 0; j < CC; ++j) s += red[tid * CC + j];
        partial[ct * B_TOT + b0 + tid] = s;
    }
}

__global__ __launch_bounds__(256)
void esenc_norm(float* __restrict__ out, const float* __restrict__ partial) {
    constexpr int ROW4 = C_CH * D_EMB / 4;             // 288 float4 per row
    constexpr int N4   = B_TOT * ROW4;
    float4* o4 = (float4*)out;
    for (int i = blockIdx.x * blockDim.x + threadIdx.x; i < N4;
         i += gridDim.x * blockDim.x) {
        const int b = i / ROW4;
        const float s = partial[b] + partial[B_TOT + b] +
                        partial[2 * B_TOT + b] + partial[3 * B_TOT + b];
        const float inv = 1.0f / sqrtf(s + 1e-10f);
        float4 v = o4[i];
        v.x *= inv; v.y *= inv; v.z *= inv; v.w *= inv;
        o4[i] = v;
    }
}

extern "C" void kernel_launch(void* const* d_in, const int* in_sizes, int n_in,
                              void* d_out, int out_size, void* d_ws, size_t ws_size,
                              hipStream_t stream) {
    const float* fcn  = (const float*)d_in[0];   // [4096,128,8,8] f32
    const float* kern = (const float*)d_in[1];   // [1,1152,8,8]  f32
    float* out = (float*)d_out;                  // [4096,1152]   f32
    float* partial = (float*)d_ws;               // [4][4096] f32 = 64 KB

    dim3 grid1((B_TOT / BT) * NCT), block1(THREADS);
    hipLaunchKernelGGL(esenc_main, grid1, block1, 0, stream, fcn, kern, out, partial);

    dim3 grid2(2048), block2(256);
    hipLaunchKernelGGL(esenc_norm, grid2, block2, 0, stream, out, partial);
}

// Round 3
// 37.158 us; speedup vs baseline: 1.6246x; 1.4710x over previous
//
#include <hip/hip_runtime.h>

// out[b, c*9+d] = sum_hw fcn[b,c,hw] * kern[c*9+d, hw]; rows L2-normalized.
// B=4096, C=128, D=9, HW=64, all fp32.
//
// K1: 8-lane group = 1 channel; lane owns 8 hw floats. kern in REGISTERS
//     (18 float4/thread). fcn loads 128B-contiguous per group (coalesced).
//     Dot finished with 3 shfl_xor rounds (width 8); lane r keeps row r.
//     Per-(ctile,row) sumsq partials -> ws. No LDS data tile, no main barriers.
// K2: out *= rsqrt(sum of 4 partials + eps).

constexpr int B_TOT  = 4096;
constexpr int C_CH   = 128;
constexpr int D_EMB  = 9;
constexpr int THREADS = 256;
constexpr int GPB    = 32;   // channel-groups (channels) per block
constexpr int RB     = 16;   // rows per block
constexpr int CHK    = 8;    // rows per chunk (= lanes per group)

__global__ __launch_bounds__(THREADS, 3)
void esenc_main(const float* __restrict__ fcn,
                const float* __restrict__ kern,
                float* __restrict__ out,
                float* __restrict__ partial) {
    __shared__ float red[THREADS];
    const int tid = threadIdx.x;
    const int l   = tid & 7;          // lane in group = hw-slice, later row id
    const int g   = tid >> 3;         // group = channel within tile
    const int ct  = blockIdx.x & 3;
    const int bt  = blockIdx.x >> 2;
    const int c   = ct * GPB + g;
    const int b0  = bt * RB;

    const float4* kern4 = (const float4*)kern;
    const float4* f4    = (const float4*)fcn;

    // kern for this channel, register-resident: 9 d x 8 floats per lane
    float4 k0[D_EMB], k1[D_EMB];
#pragma unroll
    for (int d = 0; d < D_EMB; ++d) {
        const size_t kb = (size_t)(c * D_EMB + d) * 16;
        k0[d] = kern4[kb + l];
        k1[d] = kern4[kb + 8 + l];
    }

#pragma unroll
    for (int chk = 0; chk < RB / CHK; ++chk) {
        const int bb = b0 + chk * CHK;

        // software-pipelined row loop (prefetch next row's 2 float4)
        size_t fb = ((size_t)bb * C_CH + c) * 16;
        float4 a0 = f4[fb + l];
        float4 a1 = f4[fb + 8 + l];

        float keep[D_EMB];
#pragma unroll
        for (int d = 0; d < D_EMB; ++d) keep[d] = 0.0f;

#pragma unroll
        for (int r = 0; r < CHK; ++r) {
            const float4 c0 = a0, c1 = a1;
            if (r + 1 < CHK) {
                const size_t fn = ((size_t)(bb + r + 1) * C_CH + c) * 16;
                a0 = f4[fn + l];
                a1 = f4[fn + 8 + l];
            }
            float p[D_EMB];
#pragma unroll
            for (int d = 0; d < D_EMB; ++d) {
                float t;
                t = c0.x * k0[d].x;
                t = fmaf(c0.y, k0[d].y, t);
                t = fmaf(c0.z, k0[d].z, t);
                t = fmaf(c0.w, k0[d].w, t);
                t = fmaf(c1.x, k1[d].x, t);
                t = fmaf(c1.y, k1[d].y, t);
                t = fmaf(c1.z, k1[d].z, t);
                t = fmaf(c1.w, k1[d].w, t);
                p[d] = t;
            }
            // reduce over the 8 hw-lanes
#pragma unroll
            for (int m = 1; m < 8; m <<= 1) {
#pragma unroll
                for (int d = 0; d < D_EMB; ++d)
                    p[d] += __shfl_xor(p[d], m, 8);
            }
            if (l == r) {
#pragma unroll
                for (int d = 0; d < D_EMB; ++d) keep[d] = p[d];
            }
        }

        // lane l owns row bb+l: store 9 floats + row/channel sumsq
        float* op = out + (size_t)(bb + l) * (C_CH * D_EMB) + c * D_EMB;
        float s = 0.0f;
#pragma unroll
        for (int d = 0; d < D_EMB; ++d) {
            op[d] = keep[d];
            s = fmaf(keep[d], keep[d], s);
        }

        if (chk) __syncthreads();          // red[] reuse guard
        red[tid] = s;
        __syncthreads();
        if (tid < CHK) {
            float t = 0.0f;
#pragma unroll
            for (int gg = 0; gg < GPB; ++gg) t += red[gg * 8 + tid];
            partial[ct * B_TOT + bb + tid] = t;
        }
    }
}

__global__ __launch_bounds__(256)
void esenc_norm(float* __restrict__ out, const float* __restrict__ partial) {
    constexpr int ROW4 = C_CH * D_EMB / 4;             // 288 float4 per row
    constexpr int N4   = B_TOT * ROW4;
    float4* o4 = (float4*)out;
    for (int i = blockIdx.x * blockDim.x + threadIdx.x; i < N4;
         i += gridDim.x * blockDim.x) {
        const int b = i / ROW4;
        const float s = partial[b] + partial[B_TOT + b] +
                        partial[2 * B_TOT + b] + partial[3 * B_TOT + b];
        const float inv = 1.0f / sqrtf(s + 1e-10f);
        float4 v = o4[i];
        v.x *= inv; v.y *= inv; v.z *= inv; v.w *= inv;
        o4[i] = v;
    }
}

extern "C" void kernel_launch(void* const* d_in, const int* in_sizes, int n_in,
                              void* d_out, int out_size, void* d_ws, size_t ws_size,
                              hipStream_t stream) {
    const float* fcn  = (const float*)d_in[0];   // [4096,128,8,8] f32
    const float* kern = (const float*)d_in[1];   // [1,1152,8,8]  f32
    float* out = (float*)d_out;                  // [4096,1152]   f32
    float* partial = (float*)d_ws;               // [4][4096] f32 = 64 KB

    dim3 grid1((B_TOT / RB) * (C_CH / GPB)), block1(THREADS);  // 1024 blocks
    hipLaunchKernelGGL(esenc_main, grid1, block1, 0, stream, fcn, kern, out, partial);

    dim3 grid2(2048), block2(256);
    hipLaunchKernelGGL(esenc_norm, grid2, block2, 0, stream, out, partial);
}

// Round 4
// 36.797 us; speedup vs baseline: 1.6405x; 1.0098x over previous
//
#include <hip/hip_runtime.h>

// Fused: out[b, c*9+d] = sum_hw fcn[b,c,hw] * kern[c*9+d, hw], row-L2-normalized.
// B=4096, C=128, D=9, HW=64, all fp32. ONE kernel, fcn read once, out written once.
//
// Block = 256 thr = 32 groups x 8 lanes; RB=8 rows/block; grid=512.
// Each group loops NCH=4 channels (c = ch*32 + g); kern regs (18 float4)
// reused per channel; keep[4][9] persists. Dot over hw: lane owns 8 floats,
// 3 shfl_xor rounds (width 8), lane r keeps row r. Row norm fused:
// 3 shfl_xor (masks 8/16/32) + 4x8 LDS reduce -> rsqrt -> scale -> store.

constexpr int B_TOT = 4096;
constexpr int C_CH  = 128;
constexpr int D_EMB = 9;
constexpr int THREADS = 256;
constexpr int GPB = 32;   // groups (channels concurrently) per block
constexpr int NCH = 4;    // channel iterations per group
constexpr int RB  = 8;    // rows per block (= lanes per group)

__global__ __launch_bounds__(THREADS)
void esenc_fused(const float* __restrict__ fcn,
                 const float* __restrict__ kern,
                 float* __restrict__ out) {
    __shared__ float red[4 * RB];   // 4 waves x 8 rows
    __shared__ float invn[RB];

    const int tid = threadIdx.x;
    const int l   = tid & 7;        // hw-slice lane, later row id
    const int g   = tid >> 3;       // group 0..31
    const int w   = tid >> 6;       // wave 0..3
    const int b0  = blockIdx.x * RB;

    const float4* kern4 = (const float4*)kern;
    const float4* f4    = (const float4*)fcn;

    float keep[NCH][D_EMB];

#pragma unroll
    for (int ch = 0; ch < NCH; ++ch) {
        const int c = ch * GPB + g;

        // kern for this channel: 9 d x 8 floats per lane (reused register block)
        float4 k0[D_EMB], k1[D_EMB];
#pragma unroll
        for (int d = 0; d < D_EMB; ++d) {
            const size_t kb = (size_t)(c * D_EMB + d) * 16;
            k0[d] = kern4[kb + l];
            k1[d] = kern4[kb + 8 + l];
        }

        // row rotation with 1-deep prefetch
        const size_t fb = ((size_t)b0 * C_CH + c) * 16;
        float4 a0 = f4[fb + l];
        float4 a1 = f4[fb + 8 + l];

#pragma unroll
        for (int r = 0; r < RB; ++r) {
            const float4 c0 = a0, c1 = a1;
            if (r + 1 < RB) {
                const size_t fn = ((size_t)(b0 + r + 1) * C_CH + c) * 16;
                a0 = f4[fn + l];
                a1 = f4[fn + 8 + l];
            }
            float p[D_EMB];
#pragma unroll
            for (int d = 0; d < D_EMB; ++d) {
                float t;
                t = c0.x * k0[d].x;
                t = fmaf(c0.y, k0[d].y, t);
                t = fmaf(c0.z, k0[d].z, t);
                t = fmaf(c0.w, k0[d].w, t);
                t = fmaf(c1.x, k1[d].x, t);
                t = fmaf(c1.y, k1[d].y, t);
                t = fmaf(c1.z, k1[d].z, t);
                t = fmaf(c1.w, k1[d].w, t);
                p[d] = t;
            }
#pragma unroll
            for (int m = 1; m < 8; m <<= 1) {
#pragma unroll
                for (int d = 0; d < D_EMB; ++d)
                    p[d] += __shfl_xor(p[d], m, 8);
            }
            if (l == r) {
#pragma unroll
                for (int d = 0; d < D_EMB; ++d) keep[ch][d] = p[d];
            }
        }
    }

    // per-thread sumsq for (row l, its 4 channels), reduce over 32 groups
    float s = 0.0f;
#pragma unroll
    for (int ch = 0; ch < NCH; ++ch)
#pragma unroll
        for (int d = 0; d < D_EMB; ++d)
            s = fmaf(keep[ch][d], keep[ch][d], s);

    s += __shfl_xor(s, 8,  64);   // reduce over the wave's 8 groups
    s += __shfl_xor(s, 16, 64);
    s += __shfl_xor(s, 32, 64);
    if ((tid & 63) < 8) red[w * RB + l] = s;
    __syncthreads();
    if (tid < RB) {
        const float t = red[tid] + red[RB + tid] + red[2 * RB + tid] + red[3 * RB + tid];
        invn[tid] = 1.0f / sqrtf(t + 1e-10f);
    }
    __syncthreads();
    const float inv = invn[l];

    // lane l owns row b0+l: store 4 channels x 9 floats, normalized
#pragma unroll
    for (int ch = 0; ch < NCH; ++ch) {
        const int c = ch * GPB + g;
        float* op = out + (size_t)(b0 + l) * (C_CH * D_EMB) + c * D_EMB;
#pragma unroll
        for (int d = 0; d < D_EMB; ++d)
            op[d] = keep[ch][d] * inv;
    }
}

extern "C" void kernel_launch(void* const* d_in, const int* in_sizes, int n_in,
                              void* d_out, int out_size, void* d_ws, size_t ws_size,
                              hipStream_t stream) {
    const float* fcn  = (const float*)d_in[0];   // [4096,128,8,8] f32
    const float* kern = (const float*)d_in[1];   // [1,1152,8,8]  f32
    float* out = (float*)d_out;                  // [4096,1152]   f32

    dim3 grid(B_TOT / RB), block(THREADS);       // 512 blocks
    hipLaunchKernelGGL(esenc_fused, grid, block, 0, stream, fcn, kern, out);
}